// Round 1
// baseline (5451.776 us; speedup 1.0000x reference)
//
#include <hip/hip_runtime.h>

#define B_    4
#define N1_   16384
#define M1_   2048
#define M2_   512
#define KNN_  32
#define PROJ_ 64
#define C1_   128
#define C2_   256

__device__ __forceinline__ float sqdist_exact(float px, float py, float pz,
                                              float cx, float cy, float cz) {
    // Must match numpy: ((dx*dx + dy*dy) + dz*dz), no FMA contraction.
    float dx = __fsub_rn(px, cx);
    float dy = __fsub_rn(py, cy);
    float dz = __fsub_rn(pz, cz);
    return __fadd_rn(__fadd_rn(__fmul_rn(dx, dx), __fmul_rn(dy, dy)), __fmul_rn(dz, dz));
}

// ---------------- projection: feats0[b,n,c] = xyz[b,n,:] @ Wp + bp ----------------
__global__ void __launch_bounds__(256)
proj_kernel(const float* __restrict__ xyz, const float* __restrict__ Wp,
            const float* __restrict__ bp, float* __restrict__ feats0) {
    int tid = blockIdx.x * 256 + threadIdx.x;
    int c = tid & (PROJ_ - 1);
    int pn = tid >> 6;
    if (pn >= B_ * N1_) return;
    const float* p = xyz + (size_t)pn * 3;
    float acc = p[0] * Wp[0 * PROJ_ + c];
    acc = __fmaf_rn(p[1], Wp[1 * PROJ_ + c], acc);
    acc = __fmaf_rn(p[2], Wp[2 * PROJ_ + c], acc);
    feats0[tid] = acc + bp[c];
}

// ---------------- farthest point sampling ----------------
// Serial-latency-bound (data fully cache-resident; 1 CU per batch).
// key = (f32bits(dmin) << 32) | ~gidx : u64 max == max value, tie -> min index
// (exactly jnp.argmax first-occurrence semantics; d >= 0 so f32 bits monotone).
// Round-5: replace the u64 __shfl_xor butterfly (6 chained LDS-crossbar ops,
// ~100+ cyc each) with a gfx9 DPP max-scan (row_shr 1/2/4/8 + row_bcast15/31,
// VALU-rate). Identity-0 trick makes row_mask/bound_ctrl semantics safe:
// disabled/invalid lanes yield 0, and every valid key is > 0 (~gi != 0).
template<int CTRL, int RM>
__device__ __forceinline__ unsigned long long dpp_umax64(unsigned long long pk) {
    unsigned lo = (unsigned)__builtin_amdgcn_update_dpp(
        0, (int)(unsigned)pk, CTRL, RM, 0xf, true);
    unsigned hi = (unsigned)__builtin_amdgcn_update_dpp(
        0, (int)(unsigned)(pk >> 32), CTRL, RM, 0xf, true);
    unsigned long long o = ((unsigned long long)hi << 32) | (unsigned long long)lo;
    return (o > pk) ? o : pk;
}

template<int N, int M, int NT>
__device__ __forceinline__ void fps_body(const float* __restrict__ pts,
                                         float* __restrict__ centers) {
    constexpr int PPT = N / NT;
    constexpr int NW  = NT / 64;
    const int b = blockIdx.x;
    const int t = threadIdx.x;
    const int w = t >> 6;
    const int lane = t & 63;
    const float* P = pts + (size_t)b * N * 3;
    float* C = centers + (size_t)b * M * 3;

    float px[PPT], py[PPT], pz[PPT], dmin[PPT];
#pragma unroll
    for (int k = 0; k < PPT; ++k) {
        int j = k * NT + t;
        px[k] = P[j * 3 + 0];
        py[k] = P[j * 3 + 1];
        pz[k] = P[j * 3 + 2];
        dmin[k] = 1e10f;
    }
    // Pin: values become asm outputs -> compiler cannot rematerialize the loads.
#pragma unroll
    for (int k = 0; k < PPT; ++k)
        asm volatile("" : "+v"(px[k]), "+v"(py[k]), "+v"(pz[k]), "+v"(dmin[k]));

    __shared__ alignas(16) unsigned long long wkey[2][NW];  // parity double-buffered

    float cx = P[0], cy = P[1], cz = P[2];

    for (int m = 0; m < M; ++m) {
        if (t == 0) { C[m * 3 + 0] = cx; C[m * 3 + 1] = cy; C[m * 3 + 2] = cz; }
        if (m == M - 1) break;
        const int par = m & 1;
        // ---- A: update dmin; per-lane argmax (first k on ties via strict >)
        float bv = -1.0f; int bk = 0;
#pragma unroll
        for (int k = 0; k < PPT; ++k) {
            float d  = sqdist_exact(px[k], py[k], pz[k], cx, cy, cz);
            float nd = fminf(dmin[k], d);
            dmin[k] = nd;
            bool gt = nd > bv;
            bv = gt ? nd : bv;
            bk = gt ? k : bk;
        }
        // ---- B: pack (value, ~gidx); wave max via DPP scan (no LDS crossbar)
        unsigned gi = (unsigned)(bk * NT + t);
        unsigned long long pk =
            ((unsigned long long)__float_as_uint(bv) << 32) | (unsigned)(~gi);
        pk = dpp_umax64<0x111, 0xf>(pk);   // row_shr:1
        pk = dpp_umax64<0x112, 0xf>(pk);   // row_shr:2
        pk = dpp_umax64<0x114, 0xf>(pk);   // row_shr:4
        pk = dpp_umax64<0x118, 0xf>(pk);   // row_shr:8
        pk = dpp_umax64<0x142, 0xa>(pk);   // row_bcast15 -> rows 1,3
        pk = dpp_umax64<0x143, 0xc>(pk);   // row_bcast31 -> rows 2,3
        if (lane == 63) wkey[par][w] = pk; // lane 63 holds the wave max
        __syncthreads();                   // the ONLY barrier per iter
        // ---- C: cross-wave tree reduce of NW keys (uniform, every thread)
        unsigned long long v[NW];
#pragma unroll
        for (int i = 0; i < NW; ++i) v[i] = wkey[par][i];
#pragma unroll
        for (int s = NW / 2; s > 0; s >>= 1)
#pragma unroll
            for (int i = 0; i < s; ++i) v[i] = (v[i + s] > v[i]) ? v[i + s] : v[i];
        // ---- D: winner coords via scalar (uniform) load — cache-resident
        const unsigned widx =
            (unsigned)__builtin_amdgcn_readfirstlane((int)~(unsigned)v[0]);
        const float* cp = P + (size_t)widx * 3;
        cx = cp[0]; cy = cp[1]; cz = cp[2];
    }
}

__global__ __attribute__((amdgpu_flat_work_group_size(1024, 1024)))
__attribute__((amdgpu_waves_per_eu(4, 4)))
void fps1_kernel(const float* __restrict__ pts, float* __restrict__ centers) {
    // 1024 threads -> PPT=16: 64 regs of pinned state fits the 128-reg budget,
    // no AGPR/scratch shuffling; VALU wall time unchanged (same points/CU).
    fps_body<N1_, M1_, 1024>(pts, centers);
}

__global__ __attribute__((amdgpu_flat_work_group_size(256, 256)))
__attribute__((amdgpu_waves_per_eu(1, 4)))
void fps2_kernel(const float* __restrict__ pts, float* __restrict__ centers) {
    fps_body<M1_, M2_, 256>(pts, centers);
}

// ---------------- exact kNN (top-32 smallest sq-dist, tie -> smaller index) ----------------
// radix-select over float bit patterns (all d >= 0 -> monotone in uint bits)
template<int N, int M>
__global__ void __launch_bounds__(64)
knn_kernel(const float* __restrict__ pts, const float* __restrict__ centers,
           int* __restrict__ nidx) {
    constexpr int K = KNN_;
    constexpr int CAP = 224;
    const int bm = blockIdx.x;
    const int b = bm / M;
    const int lane = threadIdx.x;
    const float* P = pts + (size_t)b * N * 3;
    const float* c = centers + (size_t)bm * 3;
    const float cx = c[0], cy = c[1], cz = c[2];
    int* out = nidx + (size_t)bm * K;

    __shared__ int hist[2048];
    __shared__ unsigned int eqk[CAP];
    __shared__ int eqi[CAP];
    __shared__ int cnt_less, cnt_eq;

    unsigned int prefix = 0; int pbits = 0;
    unsigned int Tlo = 0; unsigned long long Thi = 0x100000000ull;
    int L = 0, target = K, Cbin = N;

    for (int round = 0; round < 3; ++round) {
        const int bits  = (round < 2) ? 11 : 10;
        const int nbins = 1 << bits;
        const int shift = 32 - pbits - bits;
        for (int i = lane; i < nbins; i += 64) hist[i] = 0;
        __syncthreads();
        for (int j = lane; j < N; j += 64) {
            float d = sqdist_exact(P[j * 3], P[j * 3 + 1], P[j * 3 + 2], cx, cy, cz);
            unsigned int key = __float_as_uint(d);
            if (key >= Tlo && (unsigned long long)key < Thi)
                atomicAdd(&hist[(key >> shift) & (nbins - 1)], 1);
        }
        __syncthreads();
        const int per = nbins / 64;
        int s = 0;
        for (int i = 0; i < per; ++i) s += hist[lane * per + i];
        int cum = s;
        for (int off = 1; off < 64; off <<= 1) {
            int o = __shfl_up(cum, off);
            if (lane >= off) cum += o;
        }
        int cumex = cum - s;
        bool has = (cumex < target) && (cum >= target);
        unsigned long long ball = __ballot(has);
        int src = __ffsll(ball) - 1;
        int binsel = 0, Ladd = 0, bincnt = 0;
        if (lane == src) {
            int acc = cumex;
            for (int i = 0; i < per; ++i) {
                int h = hist[lane * per + i];
                if (acc + h >= target) { binsel = lane * per + i; Ladd = acc; bincnt = h; break; }
                acc += h;
            }
        }
        binsel = __shfl(binsel, src);
        Ladd   = __shfl(Ladd, src);
        bincnt = __shfl(bincnt, src);
        L += Ladd;
        target -= Ladd;
        prefix = (prefix << bits) | (unsigned int)binsel;
        pbits += bits;
        Tlo = prefix << (32 - pbits);
        Thi = ((unsigned long long)prefix + 1ull) << (32 - pbits);
        Cbin = bincnt;
        __syncthreads();
        if (Cbin <= CAP) break;
    }

    if (lane == 0) { cnt_less = 0; cnt_eq = 0; }
    __syncthreads();

    if (Cbin <= CAP) {
        for (int j = lane; j < N; j += 64) {
            float d = sqdist_exact(P[j * 3], P[j * 3 + 1], P[j * 3 + 2], cx, cy, cz);
            unsigned int key = __float_as_uint(d);
            if (key < Tlo) {
                int p = atomicAdd(&cnt_less, 1);
                out[p] = j;
            } else if ((unsigned long long)key < Thi) {
                int p = atomicAdd(&cnt_eq, 1);
                eqk[p] = key; eqi[p] = j;
            }
        }
        __syncthreads();
        const int E = cnt_eq;
        for (int e = lane; e < E; e += 64) {
            unsigned int ke = eqk[e]; int ie = eqi[e];
            int rank = 0;
            for (int f = 0; f < E; ++f) {
                unsigned int kf = eqk[f]; int jf = eqi[f];
                rank += (kf < ke || (kf == ke && jf < ie)) ? 1 : 0;
            }
            if (rank < target) out[L + rank] = ie;
        }
    } else {
        // pbits==32: giant tie class at exact key Tlo -> take smallest indices in order
        int cnt = 0;
        for (int jb = 0; jb < N; jb += 64) {
            int j = jb + lane;
            float d = sqdist_exact(P[j * 3], P[j * 3 + 1], P[j * 3 + 2], cx, cy, cz);
            unsigned int key = __float_as_uint(d);
            if (key < Tlo) {
                int p = atomicAdd(&cnt_less, 1);
                out[p] = j;
            }
            bool eq = (key == Tlo);
            unsigned long long mb = __ballot(eq);
            int below = __popcll(mb & ((1ull << lane) - 1ull));
            if (eq && (cnt + below) < target) out[L + cnt + below] = j;
            cnt += (int)__popcll(mb);
        }
    }
}

// ---------------- grouped 2-layer MLP + max-pool over 32 neighbors ----------------
// g stored as [nf(FD) | rel(3) | pad], Wa rows remapped accordingly.
template<int NPTS, int FD, int CO, int M>
__global__ void __launch_bounds__(CO)
group_mlp_kernel(const float* __restrict__ pts, const float* __restrict__ feats,
                 const float* __restrict__ centers, const int* __restrict__ nidx,
                 const float* __restrict__ Wa, const float* __restrict__ ba,
                 const float* __restrict__ Wb, const float* __restrict__ bb,
                 float* __restrict__ outf) {
    constexpr int KN = KNN_;
    constexpr int GS = FD + 4;
    const int bm = blockIdx.x;
    const int b = bm / M;
    const int t = threadIdx.x;
    __shared__ float g[KN][GS];
    __shared__ float h1[KN][CO];
    const int* nb = nidx + (size_t)bm * KN;
    const float* cen = centers + (size_t)bm * 3;
    const float cx = cen[0], cy = cen[1], cz = cen[2];
    {
        constexpr int PARTS = CO / KN;        // 4 (L1) or 8 (L2)
        constexpr int CHUNK = FD / PARTS;     // 16
        const int kk = t / PARTS;
        const int q  = t % PARTS;
        const int j  = nb[kk];
        const float* f = feats + ((size_t)b * NPTS + j) * FD + q * CHUNK;
        float* gr = &g[kk][q * CHUNK];
#pragma unroll
        for (int u = 0; u < CHUNK / 4; ++u)
            *(float4*)(gr + 4 * u) = *(const float4*)(f + 4 * u);
        if (q == 0) {
            const float* p = pts + ((size_t)b * NPTS + j) * 3;
            g[kk][FD + 0] = __fsub_rn(p[0], cx);
            g[kk][FD + 1] = __fsub_rn(p[1], cy);
            g[kk][FD + 2] = __fsub_rn(p[2], cz);
            g[kk][FD + 3] = 0.f;
        }
    }
    __syncthreads();
    const int o = t;
    float acc[KN];
#pragma unroll
    for (int k = 0; k < KN; ++k) acc[k] = ba[o];
    for (int s4 = 0; s4 < FD / 4; ++s4) {   // nf part: stored s -> Wa row s+3
        const float w0 = Wa[(4 * s4 + 3) * CO + o];
        const float w1 = Wa[(4 * s4 + 4) * CO + o];
        const float w2 = Wa[(4 * s4 + 5) * CO + o];
        const float w3 = Wa[(4 * s4 + 6) * CO + o];
#pragma unroll
        for (int k = 0; k < KN; ++k) {
            float4 gv = *(const float4*)&g[k][4 * s4];
            acc[k] = __fmaf_rn(gv.x, w0, acc[k]);
            acc[k] = __fmaf_rn(gv.y, w1, acc[k]);
            acc[k] = __fmaf_rn(gv.z, w2, acc[k]);
            acc[k] = __fmaf_rn(gv.w, w3, acc[k]);
        }
    }
    {
        const float w0 = Wa[0 * CO + o];
        const float w1 = Wa[1 * CO + o];
        const float w2 = Wa[2 * CO + o];
#pragma unroll
        for (int k = 0; k < KN; ++k) {
            float4 gv = *(const float4*)&g[k][FD];
            acc[k] = __fmaf_rn(gv.x, w0, acc[k]);
            acc[k] = __fmaf_rn(gv.y, w1, acc[k]);
            acc[k] = __fmaf_rn(gv.z, w2, acc[k]);
        }
    }
#pragma unroll
    for (int k = 0; k < KN; ++k) h1[k][o] = fmaxf(acc[k], 0.f);
    __syncthreads();
#pragma unroll
    for (int k = 0; k < KN; ++k) acc[k] = bb[o];
    for (int s4 = 0; s4 < CO / 4; ++s4) {
        const float w0 = Wb[(4 * s4 + 0) * CO + o];
        const float w1 = Wb[(4 * s4 + 1) * CO + o];
        const float w2 = Wb[(4 * s4 + 2) * CO + o];
        const float w3 = Wb[(4 * s4 + 3) * CO + o];
#pragma unroll
        for (int k = 0; k < KN; ++k) {
            float4 hv = *(const float4*)&h1[k][4 * s4];
            acc[k] = __fmaf_rn(hv.x, w0, acc[k]);
            acc[k] = __fmaf_rn(hv.y, w1, acc[k]);
            acc[k] = __fmaf_rn(hv.z, w2, acc[k]);
            acc[k] = __fmaf_rn(hv.w, w3, acc[k]);
        }
    }
    float mx = 0.f;
#pragma unroll
    for (int k = 0; k < KN; ++k) mx = fmaxf(mx, fmaxf(acc[k], 0.f));
    outf[(size_t)bm * CO + o] = mx;
}

// ---------------- global head: [max|mean] -> relu(g@Wd1+b) -> @Wd2+b ----------------
__global__ void __launch_bounds__(256)
head_kernel(const float* __restrict__ feats2,
            const float* __restrict__ Wd1, const float* __restrict__ bd1,
            const float* __restrict__ Wd2, const float* __restrict__ bd2,
            float* __restrict__ outp) {
    const int b = blockIdx.x, t = threadIdx.x;
    __shared__ float gsh[2 * C2_];
    __shared__ float hsh[512];
    const float* F = feats2 + (size_t)b * M2_ * C2_;
    float mx = -1e30f, sm = 0.f;
    for (int r = 0; r < M2_; ++r) {
        float v = F[r * C2_ + t];
        mx = fmaxf(mx, v);
        sm += v;
    }
    gsh[t] = mx;
    gsh[C2_ + t] = sm * (1.0f / (float)M2_);
    __syncthreads();
#pragma unroll
    for (int oo = 0; oo < 2; ++oo) {
        const int o = t + oo * 256;
        float acc = bd1[o];
        for (int i = 0; i < 512; ++i)
            acc = __fmaf_rn(gsh[i], Wd1[i * 512 + o], acc);
        hsh[o] = fmaxf(acc, 0.f);
    }
    __syncthreads();
    float acc = bd2[t];
    for (int i = 0; i < 512; ++i)
        acc = __fmaf_rn(hsh[i], Wd2[i * 256 + t], acc);
    outp[b * 256 + t] = acc;
}

extern "C" void kernel_launch(void* const* d_in, const int* in_sizes, int n_in,
                              void* d_out, int out_size, void* d_ws, size_t ws_size,
                              hipStream_t stream) {
    const float* xyz = (const float*)d_in[0];
    const float* Wp  = (const float*)d_in[1];
    const float* bp  = (const float*)d_in[2];
    const float* W1a = (const float*)d_in[3];
    const float* b1a = (const float*)d_in[4];
    const float* W1b = (const float*)d_in[5];
    const float* b1b = (const float*)d_in[6];
    const float* W2a = (const float*)d_in[7];
    const float* b2a = (const float*)d_in[8];
    const float* W2b = (const float*)d_in[9];
    const float* b2b = (const float*)d_in[10];
    const float* Wd1 = (const float*)d_in[11];
    const float* bd1 = (const float*)d_in[12];
    const float* Wd2 = (const float*)d_in[13];
    const float* bd2 = (const float*)d_in[14];
    float* out = (float*)d_out;

    char* ws = (char*)d_ws;
    size_t off = 0;
    auto alloc = [&](size_t bytes) { void* p = ws + off; off += (bytes + 255) & ~(size_t)255; return p; };
    float* feats0   = (float*)alloc((size_t)B_ * N1_ * PROJ_ * 4);
    float* centers1 = (float*)alloc((size_t)B_ * M1_ * 3 * 4);
    int*   nidx1    = (int*)  alloc((size_t)B_ * M1_ * KNN_ * 4);
    float* feats1   = (float*)alloc((size_t)B_ * M1_ * C1_ * 4);
    float* centers2 = (float*)alloc((size_t)B_ * M2_ * 3 * 4);
    int*   nidx2    = (int*)  alloc((size_t)B_ * M2_ * KNN_ * 4);
    float* feats2   = (float*)alloc((size_t)B_ * M2_ * C2_ * 4);
    (void)in_sizes; (void)n_in; (void)out_size; (void)ws_size;

    proj_kernel<<<dim3(B_ * N1_ * PROJ_ / 256), dim3(256), 0, stream>>>(xyz, Wp, bp, feats0);
    fps1_kernel<<<dim3(B_), dim3(1024), 0, stream>>>(xyz, centers1);
    knn_kernel<N1_, M1_><<<dim3(B_ * M1_), dim3(64), 0, stream>>>(xyz, centers1, nidx1);
    group_mlp_kernel<N1_, PROJ_, C1_, M1_><<<dim3(B_ * M1_), dim3(C1_), 0, stream>>>(
        xyz, feats0, centers1, nidx1, W1a, b1a, W1b, b1b, feats1);
    fps2_kernel<<<dim3(B_), dim3(256), 0, stream>>>(centers1, centers2);
    knn_kernel<M1_, M2_><<<dim3(B_ * M2_), dim3(64), 0, stream>>>(centers1, centers2, nidx2);
    group_mlp_kernel<M1_, C1_, C2_, M2_><<<dim3(B_ * M2_), dim3(C2_), 0, stream>>>(
        centers1, feats1, centers2, nidx2, W2a, b2a, W2b, b2b, feats2);
    head_kernel<<<dim3(B_), dim3(256), 0, stream>>>(feats2, Wd1, bd1, Wd2, bd2, out);
}

// Round 2
// 4512.781 us; speedup vs baseline: 1.2081x; 1.2081x over previous
//
#include <hip/hip_runtime.h>

#define B_    4
#define N1_   16384
#define M1_   2048
#define M2_   512
#define KNN_  32
#define PROJ_ 64
#define C1_   128
#define C2_   256

__device__ __forceinline__ float sqdist_exact(float px, float py, float pz,
                                              float cx, float cy, float cz) {
    // Must match numpy: ((dx*dx + dy*dy) + dz*dz), no FMA contraction.
    float dx = __fsub_rn(px, cx);
    float dy = __fsub_rn(py, cy);
    float dz = __fsub_rn(pz, cz);
    return __fadd_rn(__fadd_rn(__fmul_rn(dx, dx), __fmul_rn(dy, dy)), __fmul_rn(dz, dz));
}

// ---------------- projection: feats0[b,n,c] = xyz[b,n,:] @ Wp + bp ----------------
__global__ void __launch_bounds__(256)
proj_kernel(const float* __restrict__ xyz, const float* __restrict__ Wp,
            const float* __restrict__ bp, float* __restrict__ feats0) {
    int tid = blockIdx.x * 256 + threadIdx.x;
    int c = tid & (PROJ_ - 1);
    int pn = tid >> 6;
    if (pn >= B_ * N1_) return;
    const float* p = xyz + (size_t)pn * 3;
    float acc = p[0] * Wp[0 * PROJ_ + c];
    acc = __fmaf_rn(p[1], Wp[1 * PROJ_ + c], acc);
    acc = __fmaf_rn(p[2], Wp[2 * PROJ_ + c], acc);
    feats0[tid] = acc + bp[c];
}

// ---------------- farthest point sampling ----------------
// Serial-latency-bound (data fully cache-resident; 1 CU per batch).
// key = (f32bits(dmin) << 32) | ~gidx : u64 max == max value, tie -> min index
// (exactly jnp.argmax first-occurrence semantics; d >= 0 so f32 bits monotone).
// Round-6 structure (post-mortem of the 1024-thread regression):
//  - back to NT=512 / PPT=32 / NW=8 (16-wave barrier + NW=16 LDS reduce was
//    a net +560 cyc/iter);
//  - wave reduce via gfx9 DPP max-scan (proven bit-exact in round 5):
//    row_shr 1/2/4/8 + row_bcast15/31 at VALU rate, no LDS crossbar;
//  - centers buffered in LDS, flushed once at the end: removes the per-iter
//    global store whose vmcnt(0) drain at __syncthreads stalled every wave.
template<int CTRL, int RM>
__device__ __forceinline__ unsigned long long dpp_umax64(unsigned long long pk) {
    unsigned lo = (unsigned)__builtin_amdgcn_update_dpp(
        0, (int)(unsigned)pk, CTRL, RM, 0xf, true);
    unsigned hi = (unsigned)__builtin_amdgcn_update_dpp(
        0, (int)(unsigned)(pk >> 32), CTRL, RM, 0xf, true);
    unsigned long long o = ((unsigned long long)hi << 32) | (unsigned long long)lo;
    return (o > pk) ? o : pk;
}

template<int N, int M, int NT>
__device__ __forceinline__ void fps_body(const float* __restrict__ pts,
                                         float* __restrict__ centers) {
    constexpr int PPT = N / NT;
    constexpr int NW  = NT / 64;
    const int b = blockIdx.x;
    const int t = threadIdx.x;
    const int w = t >> 6;
    const int lane = t & 63;
    const float* P = pts + (size_t)b * N * 3;
    float* C = centers + (size_t)b * M * 3;

    float px[PPT], py[PPT], pz[PPT], dmin[PPT];
#pragma unroll
    for (int k = 0; k < PPT; ++k) {
        int j = k * NT + t;
        px[k] = P[j * 3 + 0];
        py[k] = P[j * 3 + 1];
        pz[k] = P[j * 3 + 2];
        dmin[k] = 1e10f;
    }
    // Pin: values become asm outputs -> compiler cannot rematerialize the loads.
#pragma unroll
    for (int k = 0; k < PPT; ++k)
        asm volatile("" : "+v"(px[k]), "+v"(py[k]), "+v"(pz[k]), "+v"(dmin[k]));

    __shared__ alignas(16) unsigned long long wkey[2][NW];  // parity double-buffered
    __shared__ alignas(16) float cbuf[M * 3];               // centers staging (LDS)

    float cx = P[0], cy = P[1], cz = P[2];

    for (int m = 0; m < M; ++m) {
        if (t == 0) {
            cbuf[m * 3 + 0] = cx; cbuf[m * 3 + 1] = cy; cbuf[m * 3 + 2] = cz;
        }
        if (m == M - 1) break;
        const int par = m & 1;
        // ---- A: update dmin; per-lane argmax (first k on ties via strict >)
        float bv = -1.0f; int bk = 0;
#pragma unroll
        for (int k = 0; k < PPT; ++k) {
            float d  = sqdist_exact(px[k], py[k], pz[k], cx, cy, cz);
            float nd = fminf(dmin[k], d);
            dmin[k] = nd;
            bool gt = nd > bv;
            bv = gt ? nd : bv;
            bk = gt ? k : bk;
        }
        // ---- B: pack (value, ~gidx); wave max via DPP scan (no LDS crossbar).
        // Identity-0 is safe: every valid key has nonzero low word (~gi != 0).
        unsigned gi = (unsigned)(bk * NT + t);
        unsigned long long pk =
            ((unsigned long long)__float_as_uint(bv) << 32) | (unsigned)(~gi);
        pk = dpp_umax64<0x111, 0xf>(pk);   // row_shr:1
        pk = dpp_umax64<0x112, 0xf>(pk);   // row_shr:2
        pk = dpp_umax64<0x114, 0xf>(pk);   // row_shr:4
        pk = dpp_umax64<0x118, 0xf>(pk);   // row_shr:8
        pk = dpp_umax64<0x142, 0xa>(pk);   // row_bcast15 -> rows 1,3
        pk = dpp_umax64<0x143, 0xc>(pk);   // row_bcast31 -> rows 2,3
        if (lane == 63) wkey[par][w] = pk; // lane 63 holds the wave max
        __syncthreads();                   // the ONLY barrier per iter (LDS-only drain)
        // ---- C: cross-wave tree reduce of NW keys (uniform, every thread)
        unsigned long long v[NW];
#pragma unroll
        for (int i = 0; i < NW; ++i) v[i] = wkey[par][i];
#pragma unroll
        for (int s = NW / 2; s > 0; s >>= 1)
#pragma unroll
            for (int i = 0; i < s; ++i) v[i] = (v[i + s] > v[i]) ? v[i + s] : v[i];
        // ---- D: winner coords via uniform (scalar) load — cache-resident
        const unsigned widx =
            (unsigned)__builtin_amdgcn_readfirstlane((int)~(unsigned)v[0]);
        const float* cp = P + (size_t)widx * 3;
        cx = cp[0]; cy = cp[1]; cz = cp[2];
    }
    __syncthreads();
    // flush centers LDS -> global, coalesced float4
#pragma unroll 1
    for (int i = t; i < (M * 3) / 4; i += NT)
        ((float4*)C)[i] = ((const float4*)cbuf)[i];
}

__global__ __attribute__((amdgpu_flat_work_group_size(512, 512)))
__attribute__((amdgpu_waves_per_eu(2, 2)))
void fps1_kernel(const float* __restrict__ pts, float* __restrict__ centers) {
    fps_body<N1_, M1_, 512>(pts, centers);
}

__global__ __attribute__((amdgpu_flat_work_group_size(256, 256)))
__attribute__((amdgpu_waves_per_eu(1, 4)))
void fps2_kernel(const float* __restrict__ pts, float* __restrict__ centers) {
    fps_body<M1_, M2_, 256>(pts, centers);
}

// ---------------- exact kNN (top-32 smallest sq-dist, tie -> smaller index) ----------------
// radix-select over float bit patterns (all d >= 0 -> monotone in uint bits)
template<int N, int M>
__global__ void __launch_bounds__(64)
knn_kernel(const float* __restrict__ pts, const float* __restrict__ centers,
           int* __restrict__ nidx) {
    constexpr int K = KNN_;
    constexpr int CAP = 224;
    const int bm = blockIdx.x;
    const int b = bm / M;
    const int lane = threadIdx.x;
    const float* P = pts + (size_t)b * N * 3;
    const float* c = centers + (size_t)bm * 3;
    const float cx = c[0], cy = c[1], cz = c[2];
    int* out = nidx + (size_t)bm * K;

    __shared__ int hist[2048];
    __shared__ unsigned int eqk[CAP];
    __shared__ int eqi[CAP];
    __shared__ int cnt_less, cnt_eq;

    unsigned int prefix = 0; int pbits = 0;
    unsigned int Tlo = 0; unsigned long long Thi = 0x100000000ull;
    int L = 0, target = K, Cbin = N;

    for (int round = 0; round < 3; ++round) {
        const int bits  = (round < 2) ? 11 : 10;
        const int nbins = 1 << bits;
        const int shift = 32 - pbits - bits;
        for (int i = lane; i < nbins; i += 64) hist[i] = 0;
        __syncthreads();
        for (int j = lane; j < N; j += 64) {
            float d = sqdist_exact(P[j * 3], P[j * 3 + 1], P[j * 3 + 2], cx, cy, cz);
            unsigned int key = __float_as_uint(d);
            if (key >= Tlo && (unsigned long long)key < Thi)
                atomicAdd(&hist[(key >> shift) & (nbins - 1)], 1);
        }
        __syncthreads();
        const int per = nbins / 64;
        int s = 0;
        for (int i = 0; i < per; ++i) s += hist[lane * per + i];
        int cum = s;
        for (int off = 1; off < 64; off <<= 1) {
            int o = __shfl_up(cum, off);
            if (lane >= off) cum += o;
        }
        int cumex = cum - s;
        bool has = (cumex < target) && (cum >= target);
        unsigned long long ball = __ballot(has);
        int src = __ffsll(ball) - 1;
        int binsel = 0, Ladd = 0, bincnt = 0;
        if (lane == src) {
            int acc = cumex;
            for (int i = 0; i < per; ++i) {
                int h = hist[lane * per + i];
                if (acc + h >= target) { binsel = lane * per + i; Ladd = acc; bincnt = h; break; }
                acc += h;
            }
        }
        binsel = __shfl(binsel, src);
        Ladd   = __shfl(Ladd, src);
        bincnt = __shfl(bincnt, src);
        L += Ladd;
        target -= Ladd;
        prefix = (prefix << bits) | (unsigned int)binsel;
        pbits += bits;
        Tlo = prefix << (32 - pbits);
        Thi = ((unsigned long long)prefix + 1ull) << (32 - pbits);
        Cbin = bincnt;
        __syncthreads();
        if (Cbin <= CAP) break;
    }

    if (lane == 0) { cnt_less = 0; cnt_eq = 0; }
    __syncthreads();

    if (Cbin <= CAP) {
        for (int j = lane; j < N; j += 64) {
            float d = sqdist_exact(P[j * 3], P[j * 3 + 1], P[j * 3 + 2], cx, cy, cz);
            unsigned int key = __float_as_uint(d);
            if (key < Tlo) {
                int p = atomicAdd(&cnt_less, 1);
                out[p] = j;
            } else if ((unsigned long long)key < Thi) {
                int p = atomicAdd(&cnt_eq, 1);
                eqk[p] = key; eqi[p] = j;
            }
        }
        __syncthreads();
        const int E = cnt_eq;
        for (int e = lane; e < E; e += 64) {
            unsigned int ke = eqk[e]; int ie = eqi[e];
            int rank = 0;
            for (int f = 0; f < E; ++f) {
                unsigned int kf = eqk[f]; int jf = eqi[f];
                rank += (kf < ke || (kf == ke && jf < ie)) ? 1 : 0;
            }
            if (rank < target) out[L + rank] = ie;
        }
    } else {
        // pbits==32: giant tie class at exact key Tlo -> take smallest indices in order
        int cnt = 0;
        for (int jb = 0; jb < N; jb += 64) {
            int j = jb + lane;
            float d = sqdist_exact(P[j * 3], P[j * 3 + 1], P[j * 3 + 2], cx, cy, cz);
            unsigned int key = __float_as_uint(d);
            if (key < Tlo) {
                int p = atomicAdd(&cnt_less, 1);
                out[p] = j;
            }
            bool eq = (key == Tlo);
            unsigned long long mb = __ballot(eq);
            int below = __popcll(mb & ((1ull << lane) - 1ull));
            if (eq && (cnt + below) < target) out[L + cnt + below] = j;
            cnt += (int)__popcll(mb);
        }
    }
}

// ---------------- grouped 2-layer MLP + max-pool over 32 neighbors ----------------
// g stored as [nf(FD) | rel(3) | pad], Wa rows remapped accordingly.
template<int NPTS, int FD, int CO, int M>
__global__ void __launch_bounds__(CO)
group_mlp_kernel(const float* __restrict__ pts, const float* __restrict__ feats,
                 const float* __restrict__ centers, const int* __restrict__ nidx,
                 const float* __restrict__ Wa, const float* __restrict__ ba,
                 const float* __restrict__ Wb, const float* __restrict__ bb,
                 float* __restrict__ outf) {
    constexpr int KN = KNN_;
    constexpr int GS = FD + 4;
    const int bm = blockIdx.x;
    const int b = bm / M;
    const int t = threadIdx.x;
    __shared__ float g[KN][GS];
    __shared__ float h1[KN][CO];
    const int* nb = nidx + (size_t)bm * KN;
    const float* cen = centers + (size_t)bm * 3;
    const float cx = cen[0], cy = cen[1], cz = cen[2];
    {
        constexpr int PARTS = CO / KN;        // 4 (L1) or 8 (L2)
        constexpr int CHUNK = FD / PARTS;     // 16
        const int kk = t / PARTS;
        const int q  = t % PARTS;
        const int j  = nb[kk];
        const float* f = feats + ((size_t)b * NPTS + j) * FD + q * CHUNK;
        float* gr = &g[kk][q * CHUNK];
#pragma unroll
        for (int u = 0; u < CHUNK / 4; ++u)
            *(float4*)(gr + 4 * u) = *(const float4*)(f + 4 * u);
        if (q == 0) {
            const float* p = pts + ((size_t)b * NPTS + j) * 3;
            g[kk][FD + 0] = __fsub_rn(p[0], cx);
            g[kk][FD + 1] = __fsub_rn(p[1], cy);
            g[kk][FD + 2] = __fsub_rn(p[2], cz);
            g[kk][FD + 3] = 0.f;
        }
    }
    __syncthreads();
    const int o = t;
    float acc[KN];
#pragma unroll
    for (int k = 0; k < KN; ++k) acc[k] = ba[o];
    for (int s4 = 0; s4 < FD / 4; ++s4) {   // nf part: stored s -> Wa row s+3
        const float w0 = Wa[(4 * s4 + 3) * CO + o];
        const float w1 = Wa[(4 * s4 + 4) * CO + o];
        const float w2 = Wa[(4 * s4 + 5) * CO + o];
        const float w3 = Wa[(4 * s4 + 6) * CO + o];
#pragma unroll
        for (int k = 0; k < KN; ++k) {
            float4 gv = *(const float4*)&g[k][4 * s4];
            acc[k] = __fmaf_rn(gv.x, w0, acc[k]);
            acc[k] = __fmaf_rn(gv.y, w1, acc[k]);
            acc[k] = __fmaf_rn(gv.z, w2, acc[k]);
            acc[k] = __fmaf_rn(gv.w, w3, acc[k]);
        }
    }
    {
        const float w0 = Wa[0 * CO + o];
        const float w1 = Wa[1 * CO + o];
        const float w2 = Wa[2 * CO + o];
#pragma unroll
        for (int k = 0; k < KN; ++k) {
            float4 gv = *(const float4*)&g[k][FD];
            acc[k] = __fmaf_rn(gv.x, w0, acc[k]);
            acc[k] = __fmaf_rn(gv.y, w1, acc[k]);
            acc[k] = __fmaf_rn(gv.z, w2, acc[k]);
        }
    }
#pragma unroll
    for (int k = 0; k < KN; ++k) h1[k][o] = fmaxf(acc[k], 0.f);
    __syncthreads();
#pragma unroll
    for (int k = 0; k < KN; ++k) acc[k] = bb[o];
    for (int s4 = 0; s4 < CO / 4; ++s4) {
        const float w0 = Wb[(4 * s4 + 0) * CO + o];
        const float w1 = Wb[(4 * s4 + 1) * CO + o];
        const float w2 = Wb[(4 * s4 + 2) * CO + o];
        const float w3 = Wb[(4 * s4 + 3) * CO + o];
#pragma unroll
        for (int k = 0; k < KN; ++k) {
            float4 hv = *(const float4*)&h1[k][4 * s4];
            acc[k] = __fmaf_rn(hv.x, w0, acc[k]);
            acc[k] = __fmaf_rn(hv.y, w1, acc[k]);
            acc[k] = __fmaf_rn(hv.z, w2, acc[k]);
            acc[k] = __fmaf_rn(hv.w, w3, acc[k]);
        }
    }
    float mx = 0.f;
#pragma unroll
    for (int k = 0; k < KN; ++k) mx = fmaxf(mx, fmaxf(acc[k], 0.f));
    outf[(size_t)bm * CO + o] = mx;
}

// ---------------- global head: [max|mean] -> relu(g@Wd1+b) -> @Wd2+b ----------------
__global__ void __launch_bounds__(256)
head_kernel(const float* __restrict__ feats2,
            const float* __restrict__ Wd1, const float* __restrict__ bd1,
            const float* __restrict__ Wd2, const float* __restrict__ bd2,
            float* __restrict__ outp) {
    const int b = blockIdx.x, t = threadIdx.x;
    __shared__ float gsh[2 * C2_];
    __shared__ float hsh[512];
    const float* F = feats2 + (size_t)b * M2_ * C2_;
    float mx = -1e30f, sm = 0.f;
    for (int r = 0; r < M2_; ++r) {
        float v = F[r * C2_ + t];
        mx = fmaxf(mx, v);
        sm += v;
    }
    gsh[t] = mx;
    gsh[C2_ + t] = sm * (1.0f / (float)M2_);
    __syncthreads();
#pragma unroll
    for (int oo = 0; oo < 2; ++oo) {
        const int o = t + oo * 256;
        float acc = bd1[o];
        for (int i = 0; i < 512; ++i)
            acc = __fmaf_rn(gsh[i], Wd1[i * 512 + o], acc);
        hsh[o] = fmaxf(acc, 0.f);
    }
    __syncthreads();
    float acc = bd2[t];
    for (int i = 0; i < 512; ++i)
        acc = __fmaf_rn(hsh[i], Wd2[i * 256 + t], acc);
    outp[b * 256 + t] = acc;
}

extern "C" void kernel_launch(void* const* d_in, const int* in_sizes, int n_in,
                              void* d_out, int out_size, void* d_ws, size_t ws_size,
                              hipStream_t stream) {
    const float* xyz = (const float*)d_in[0];
    const float* Wp  = (const float*)d_in[1];
    const float* bp  = (const float*)d_in[2];
    const float* W1a = (const float*)d_in[3];
    const float* b1a = (const float*)d_in[4];
    const float* W1b = (const float*)d_in[5];
    const float* b1b = (const float*)d_in[6];
    const float* W2a = (const float*)d_in[7];
    const float* b2a = (const float*)d_in[8];
    const float* W2b = (const float*)d_in[9];
    const float* b2b = (const float*)d_in[10];
    const float* Wd1 = (const float*)d_in[11];
    const float* bd1 = (const float*)d_in[12];
    const float* Wd2 = (const float*)d_in[13];
    const float* bd2 = (const float*)d_in[14];
    float* out = (float*)d_out;

    char* ws = (char*)d_ws;
    size_t off = 0;
    auto alloc = [&](size_t bytes) { void* p = ws + off; off += (bytes + 255) & ~(size_t)255; return p; };
    float* feats0   = (float*)alloc((size_t)B_ * N1_ * PROJ_ * 4);
    float* centers1 = (float*)alloc((size_t)B_ * M1_ * 3 * 4);
    int*   nidx1    = (int*)  alloc((size_t)B_ * M1_ * KNN_ * 4);
    float* feats1   = (float*)alloc((size_t)B_ * M1_ * C1_ * 4);
    float* centers2 = (float*)alloc((size_t)B_ * M2_ * 3 * 4);
    int*   nidx2    = (int*)  alloc((size_t)B_ * M2_ * KNN_ * 4);
    float* feats2   = (float*)alloc((size_t)B_ * M2_ * C2_ * 4);
    (void)in_sizes; (void)n_in; (void)out_size; (void)ws_size;

    proj_kernel<<<dim3(B_ * N1_ * PROJ_ / 256), dim3(256), 0, stream>>>(xyz, Wp, bp, feats0);
    fps1_kernel<<<dim3(B_), dim3(512), 0, stream>>>(xyz, centers1);
    knn_kernel<N1_, M1_><<<dim3(B_ * M1_), dim3(64), 0, stream>>>(xyz, centers1, nidx1);
    group_mlp_kernel<N1_, PROJ_, C1_, M1_><<<dim3(B_ * M1_), dim3(C1_), 0, stream>>>(
        xyz, feats0, centers1, nidx1, W1a, b1a, W1b, b1b, feats1);
    fps2_kernel<<<dim3(B_), dim3(256), 0, stream>>>(centers1, centers2);
    knn_kernel<M1_, M2_><<<dim3(B_ * M2_), dim3(64), 0, stream>>>(centers1, centers2, nidx2);
    group_mlp_kernel<M1_, C1_, C2_, M2_><<<dim3(B_ * M2_), dim3(C2_), 0, stream>>>(
        centers1, feats1, centers2, nidx2, W2a, b2a, W2b, b2b, feats2);
    head_kernel<<<dim3(B_), dim3(256), 0, stream>>>(feats2, Wd1, bd1, Wd2, bd2, out);
}